// Round 1
// baseline (1293.155 us; speedup 1.0000x reference)
//
#include <hip/hip_runtime.h>

#define N_NODES 10000
#define N_EDGES 160000
#define DVAL    512
#define DEPTH   10

// ---------------- CSR build ----------------

__global__ void zero_int_kernel(int* p, int n) {
    int i = blockIdx.x * 256 + threadIdx.x;
    if (i < n) p[i] = 0;
}

__global__ void count_deg_kernel(const int* __restrict__ dst, int* __restrict__ deg, int n) {
    int i = blockIdx.x * 256 + threadIdx.x;
    if (i < n) atomicAdd(&deg[dst[i]], 1);
}

// single block, 1024 threads, exclusive scan of deg[10000] -> row_ptr[10001], copy to cursor
__global__ __launch_bounds__(1024) void scan_kernel(const int* __restrict__ deg,
                                                    int* __restrict__ row_ptr,
                                                    int* __restrict__ cursor) {
    __shared__ int sums[1024];
    const int tid = threadIdx.x;
    const int CH = 10;  // 10 * 1024 >= 10000
    int base = tid * CH;
    int local[CH];
    int s = 0;
#pragma unroll
    for (int i = 0; i < CH; i++) {
        int idx = base + i;
        int v = (idx < N_NODES) ? deg[idx] : 0;
        local[i] = s;  // exclusive within chunk
        s += v;
    }
    sums[tid] = s;
    __syncthreads();
    for (int off = 1; off < 1024; off <<= 1) {
        int v = (tid >= off) ? sums[tid - off] : 0;
        __syncthreads();
        sums[tid] += v;
        __syncthreads();
    }
    int chunk_base = (tid > 0) ? sums[tid - 1] : 0;
#pragma unroll
    for (int i = 0; i < CH; i++) {
        int idx = base + i;
        if (idx < N_NODES) {
            int v = chunk_base + local[i];
            row_ptr[idx] = v;
            cursor[idx] = v;
        }
    }
    if (tid == 1023) row_ptr[N_NODES] = sums[1023];
}

__global__ void fill_edges_kernel(const int* __restrict__ src, const int* __restrict__ dst,
                                  int* __restrict__ cursor, int* __restrict__ esrc, int n) {
    int i = blockIdx.x * 256 + threadIdx.x;
    if (i < n) {
        int p = atomicAdd(&cursor[dst[i]], 1);
        esrc[p] = src[i];
    }
}

// ---------------- layer kernels ----------------

// input aggregation: F_IN = 6 floats per node
__global__ __launch_bounds__(64) void aggregate6_kernel(const float* __restrict__ feat,
                                                        const int* __restrict__ row_ptr,
                                                        const int* __restrict__ esrc,
                                                        float* __restrict__ agg6) {
    int node = blockIdx.x;
    int l = threadIdx.x;
    if (l >= 6) return;
    int start = row_ptr[node], end = row_ptr[node + 1];
    float acc = 0.f;
    for (int e = start; e < end; e++) acc += feat[esrc[e] * 6 + l];
    agg6[node * 6 + l] = acc;
}

// x = relu(agg6 @ W_in + b_in)   [10000 x 512], K = 6
__global__ __launch_bounds__(256) void input_layer_kernel(const float* __restrict__ agg6,
                                                          const float* __restrict__ W_in,
                                                          const float* __restrict__ b_in,
                                                          float* __restrict__ x) {
    int node = blockIdx.x;
    int j = threadIdx.x;
    float a[6];
#pragma unroll
    for (int k = 0; k < 6; k++) a[k] = agg6[node * 6 + k];
#pragma unroll
    for (int r = 0; r < 2; r++) {
        int jj = j + r * 256;
        float s = b_in[jj];
#pragma unroll
        for (int k = 0; k < 6; k++) s += a[k] * W_in[k * 512 + jj];
        x[(size_t)node * 512 + jj] = fmaxf(s, 0.f);
    }
}

// agg[node, :] = sum over incoming edges of x[src, :]   (D=512)
// one block (128 threads) per node, each thread owns a float4 column slice
__global__ __launch_bounds__(128) void aggregate512_kernel(const float* __restrict__ x,
                                                           const int* __restrict__ row_ptr,
                                                           const int* __restrict__ esrc,
                                                           float* __restrict__ agg) {
    int node = blockIdx.x;
    int col = threadIdx.x * 4;
    int start = row_ptr[node], end = row_ptr[node + 1];
    float4 acc = make_float4(0.f, 0.f, 0.f, 0.f);
    for (int e = start; e < end; e++) {
        int s = esrc[e];
        float4 v = *(const float4*)(x + (size_t)s * 512 + col);
        acc.x += v.x; acc.y += v.y; acc.z += v.z; acc.w += v.w;
    }
    *(float4*)(agg + (size_t)node * 512 + col) = acc;
}

// C[M,512] = A[M,512] @ W[512,512] + bias ; fp32 tiled
#define BM 64
#define BN 64
#define BK 16
__global__ __launch_bounds__(256) void gemm_bias_kernel(const float* __restrict__ A,
                                                        const float* __restrict__ W,
                                                        const float* __restrict__ bias,
                                                        float* __restrict__ C, int M) {
    __shared__ float As[BK][BM + 4];
    __shared__ float Bs[BK][BN + 4];
    const int bm = blockIdx.x * BM;
    const int bn = blockIdx.y * BN;
    const int tid = threadIdx.x;
    const int tx = tid & 15;
    const int ty = tid >> 4;
    const int ar = tid >> 2;
    const int ac = (tid & 3) << 2;
    const int br = tid >> 4;
    const int bc = (tid & 15) << 2;
    float c[4][4] = {};
    for (int kb = 0; kb < 512; kb += BK) {
        float4 av;
        int arow = bm + ar;
        if (arow < M) av = *(const float4*)(A + (size_t)arow * 512 + kb + ac);
        else av = make_float4(0.f, 0.f, 0.f, 0.f);
        float4 bv = *(const float4*)(W + (size_t)(kb + br) * 512 + bn + bc);
        As[ac + 0][ar] = av.x;
        As[ac + 1][ar] = av.y;
        As[ac + 2][ar] = av.z;
        As[ac + 3][ar] = av.w;
        *(float4*)&Bs[br][bc] = bv;
        __syncthreads();
#pragma unroll
        for (int k = 0; k < BK; k++) {
            float4 a4 = *(const float4*)&As[k][ty * 4];
            float4 b4 = *(const float4*)&Bs[k][tx * 4];
            float ai[4] = {a4.x, a4.y, a4.z, a4.w};
            float bj[4] = {b4.x, b4.y, b4.z, b4.w};
#pragma unroll
            for (int i = 0; i < 4; i++)
#pragma unroll
                for (int j = 0; j < 4; j++) c[i][j] += ai[i] * bj[j];
        }
        __syncthreads();
    }
#pragma unroll
    for (int i = 0; i < 4; i++) {
        int row = bm + ty * 4 + i;
        if (row >= M) continue;
        int col = bn + tx * 4;
        float4 bv = *(const float4*)(bias + col);
        float4 o = make_float4(c[i][0] + bv.x, c[i][1] + bv.y, c[i][2] + bv.z, c[i][3] + bv.w);
        *(float4*)(C + (size_t)row * 512 + col) = o;
    }
}

// out[node] = dot(x[node,:], W_out) + b_out   (one wave per node)
__global__ __launch_bounds__(256) void output_layer_kernel(const float* __restrict__ x,
                                                           const float* __restrict__ W_out,
                                                           const float* __restrict__ b_out,
                                                           float* __restrict__ out) {
    int wave = threadIdx.x >> 6;
    int lane = threadIdx.x & 63;
    int node = blockIdx.x * 4 + wave;
    if (node >= N_NODES) return;
    float s = 0.f;
#pragma unroll
    for (int r = 0; r < 8; r++) {
        int k = lane + r * 64;
        s += x[(size_t)node * 512 + k] * W_out[k];
    }
#pragma unroll
    for (int off = 32; off > 0; off >>= 1) s += __shfl_down(s, off, 64);
    if (lane == 0) out[node] = s + b_out[0];
}

// ---------------- launch ----------------

extern "C" void kernel_launch(void* const* d_in, const int* in_sizes, int n_in,
                              void* d_out, int out_size, void* d_ws, size_t ws_size,
                              hipStream_t stream) {
    const float* features = (const float*)d_in[0];  // [10000, 6]
    const float* W_in     = (const float*)d_in[1];  // [6, 512]
    const float* b_in     = (const float*)d_in[2];  // [512]
    const float* Ws       = (const float*)d_in[3];  // [10, 512, 512]
    const float* bs       = (const float*)d_in[4];  // [10, 512]
    const float* W_out    = (const float*)d_in[5];  // [512, 1]
    const float* b_out    = (const float*)d_in[6];  // [1]
    const int*   src      = (const int*)d_in[7];    // [160000]
    const int*   dst      = (const int*)d_in[8];    // [160000]
    float* out = (float*)d_out;

    // workspace layout
    char* p = (char*)d_ws;
    auto alloc = [&](size_t bytes) {
        char* r = p;
        p += (bytes + 255) & ~size_t(255);
        return r;
    };
    float* x    = (float*)alloc((size_t)N_NODES * DVAL * 4);
    float* agg  = (float*)alloc((size_t)N_NODES * DVAL * 4);
    float* agg6 = (float*)alloc((size_t)N_NODES * 6 * 4);
    int* deg     = (int*)alloc((size_t)N_NODES * 4);
    int* row_ptr = (int*)alloc((size_t)(N_NODES + 1) * 4);
    int* cursor  = (int*)alloc((size_t)N_NODES * 4);
    int* esrc    = (int*)alloc((size_t)N_EDGES * 4);

    // CSR build
    zero_int_kernel<<<(N_NODES + 255) / 256, 256, 0, stream>>>(deg, N_NODES);
    count_deg_kernel<<<(N_EDGES + 255) / 256, 256, 0, stream>>>(dst, deg, N_EDGES);
    scan_kernel<<<1, 1024, 0, stream>>>(deg, row_ptr, cursor);
    fill_edges_kernel<<<(N_EDGES + 255) / 256, 256, 0, stream>>>(src, dst, cursor, esrc, N_EDGES);

    // input layer
    aggregate6_kernel<<<N_NODES, 64, 0, stream>>>(features, row_ptr, esrc, agg6);
    input_layer_kernel<<<N_NODES, 256, 0, stream>>>(agg6, W_in, b_in, x);

    // hidden layers
    dim3 ggrid((N_NODES + BM - 1) / BM, 512 / BN);
    for (int l = 0; l < DEPTH; l++) {
        aggregate512_kernel<<<N_NODES, 128, 0, stream>>>(x, row_ptr, esrc, agg);
        gemm_bias_kernel<<<ggrid, 256, 0, stream>>>(agg, Ws + (size_t)l * 512 * 512,
                                                    bs + (size_t)l * 512, x, N_NODES);
    }

    // output layer
    output_layer_kernel<<<(N_NODES + 3) / 4, 256, 0, stream>>>(x, W_out, b_out, out);
}